// Round 4
// baseline (403.164 us; speedup 1.0000x reference)
//
#include <hip/hip_runtime.h>
#include <hip/hip_bf16.h>

#define T_TOK 2048
#define HID 2048
#define IMED 768
#define NEXP 16
#define TOPK 8
#define MAXPAIR (T_TOK * TOPK)

using f32x4  = __attribute__((ext_vector_type(4))) float;
using bf16x8 = __attribute__((ext_vector_type(8))) __bf16;

__device__ __forceinline__ f32x4 mfma16(bf16x8 a, bf16x8 b, f32x4 c) {
  return __builtin_amdgcn_mfma_f32_16x16x32_bf16(a, b, c, 0, 0, 0);
}

__device__ __forceinline__ void gload16(const void* g, void* lds) {
  __builtin_amdgcn_global_load_lds((const __attribute__((address_space(1))) unsigned int*)g,
                                   (__attribute__((address_space(3))) unsigned int*)lds,
                                   16, 0, 0);
}

#define BAR() do { asm volatile("s_barrier" ::: "memory"); \
                   __builtin_amdgcn_sched_barrier(0); } while (0)
#define WAITV(N) asm volatile("s_waitcnt vmcnt(" #N ")" ::: "memory")

// ---------- prep: fp32 -> bf16 copy of hidden_states ----------
__global__ void moe_cvt_x(const float* __restrict__ X, __bf16* __restrict__ XB) {
  int i = (blockIdx.x * blockDim.x + threadIdx.x) * 8;
  float4 v0 = *(const float4*)&X[i];
  float4 v1 = *(const float4*)&X[i + 4];
  bf16x8 o;
  o[0] = (__bf16)v0.x; o[1] = (__bf16)v0.y; o[2] = (__bf16)v0.z; o[3] = (__bf16)v0.w;
  o[4] = (__bf16)v1.x; o[5] = (__bf16)v1.y; o[6] = (__bf16)v1.z; o[7] = (__bf16)v1.w;
  *(bf16x8*)&XB[i] = o;
}

// ---------- prep: per-expert transpose [R][C] f32 -> [C][R] bf16, 64x64 tiles ----------
// f32 LDS tile, b128 writes, b32 reads (vs old 16x ds_write_b16 + 16x ds_read_u16).
__global__ __launch_bounds__(256) void moe_transpose(const float* __restrict__ in,
                                                     __bf16* __restrict__ out,
                                                     int R, int C) {
  __shared__ __align__(16) float tile[64][68];   // 272B row stride, 16B-aligned
  const int e = blockIdx.z;
  const float* ib = in + (size_t)e * R * C;
  __bf16* ob = out + (size_t)e * R * C;
  const int c0 = blockIdx.x * 64, r0 = blockIdx.y * 64;
  const int tid = threadIdx.x;
  const int lr = tid >> 4;            // 0..15
  const int lc = (tid & 15) * 4;      // 0..60
#pragma unroll
  for (int i = 0; i < 4; ++i) {
    int r = lr + i * 16;
    float4 v = *(const float4*)&ib[(size_t)(r0 + r) * C + c0 + lc];
    *(float4*)&tile[r][lc] = v;
  }
  __syncthreads();
  const int oc = tid >> 2;            // out row (orig col) 0..63
  const int sr = (tid & 3) * 16;      // r-chunk
  bf16x8 o0, o1;
#pragma unroll
  for (int j = 0; j < 8; ++j) o0[j] = (__bf16)tile[sr + j][oc];
#pragma unroll
  for (int j = 0; j < 8; ++j) o1[j] = (__bf16)tile[sr + 8 + j][oc];
  *(bf16x8*)&ob[(size_t)(c0 + oc) * R + r0 + sr] = o0;
  *(bf16x8*)&ob[(size_t)(c0 + oc) * R + r0 + sr + 8] = o1;
}

// ---------- routing ----------
// meta ints: [0..15]=counts  [16..32]=offsets(17)  [33..48]=cursors
__global__ void moe_route_build(const int* __restrict__ idx, const float* __restrict__ wgt,
                                float* __restrict__ combine, int* __restrict__ meta) {
  int t = blockIdx.x * blockDim.x + threadIdx.x;
  if (t >= T_TOK) return;
  float c[NEXP];
#pragma unroll
  for (int e = 0; e < NEXP; ++e) c[e] = 0.f;
  for (int k = 0; k < TOPK; ++k) c[idx[t * TOPK + k]] += wgt[t * TOPK + k];
  for (int e = 0; e < NEXP; ++e) {
    combine[t * NEXP + e] = c[e];
    if (c[e] != 0.f) atomicAdd(&meta[e], 1);
  }
}

__global__ void moe_scan(int* __restrict__ meta) {
  if (threadIdx.x == 0 && blockIdx.x == 0) {
    int s = 0;
    for (int e = 0; e < NEXP; ++e) { meta[16 + e] = s; meta[33 + e] = s; s += meta[e]; }
    meta[32] = s;
  }
}

__global__ void moe_scatter(const float* __restrict__ combine, int* __restrict__ meta,
                            int* __restrict__ route_tok, float* __restrict__ route_w) {
  int t = blockIdx.x * blockDim.x + threadIdx.x;
  if (t >= T_TOK) return;
  for (int e = 0; e < NEXP; ++e) {
    float c = combine[t * NEXP + e];
    if (c != 0.f) {
      int p = atomicAdd(&meta[33 + e], 1);
      route_tok[p] = t;
      route_w[p] = c;
    }
  }
}

// ---------- GEMM1: BM=128 pairs x BN=256 B-rows (128 gate + 128 up, interleaved
// per-wave), K=2048. 8 waves (2Mx4N), wave tile 64x64. 3-buf counted-vmcnt pipeline.
__global__ __launch_bounds__(512, 2) void moe_gemm1(
    const __bf16* __restrict__ XB, const __bf16* __restrict__ WguT,
    const int* __restrict__ rtok, const float* __restrict__ rw,
    const int* __restrict__ meta, __bf16* __restrict__ ACT) {
  // 1536 WGs = 8 XCDs x 192; consecutive wgid = m-blocks of one (e,ny) panel.
  const int orig = blockIdx.x;
  const int wgid = (orig & 7) * 192 + (orig >> 3);
  const int e   = wgid / 96;
  const int rem = wgid % 96;
  const int ny  = rem >> 4;
  const int mx  = rem & 15;

  const int seg0 = meta[16 + e];
  const int cnt  = meta[16 + e + 1] - seg0;
  const int m0 = mx * 128;
  if (m0 >= cnt) return;
  const int n0 = ny * 128;            // I-col base (128 I-cols per tile)

  __shared__ __align__(16) char As[3 * 16384];   // 3 x (128 rows x 128B)
  __shared__ __align__(16) char Bs[3 * 32768];   // 3 x (256 rows x 128B)

  const int tid = threadIdx.x;
  const int l = tid & 63;
  const int w = tid >> 6;             // 0..7
  const int wm = w >> 2, wn = w & 3;
  const int swoff = 16 * ((l & 7) ^ (l >> 3));

  const char* baseA[2];
  const char* baseB[4];
#pragma unroll
  for (int q = 0; q < 2; ++q) {
    const int r = (w * 2 + q) * 8 + (l >> 3);     // 0..127
    int grow = m0 + r; if (grow >= cnt) grow = cnt - 1;
    const int tok = rtok[seg0 + grow];
    baseA[q] = (const char*)(XB + (size_t)tok * HID) + swoff;
  }
#pragma unroll
  for (int q = 0; q < 4; ++q) {
    const int r = (w * 4 + q) * 8 + (l >> 3);     // 0..255
    const int s = r & 63;
    const int wr = (s < 32) ? (n0 + (r >> 6) * 32 + s)
                            : (IMED + n0 + (r >> 6) * 32 + (s - 32));
    baseB[q] = (const char*)(WguT + ((size_t)e * (2 * IMED) + wr) * HID) + swoff;
  }

  f32x4 acc[4][4];   // ni 0,1 = gate ; 2,3 = up (same I-cols)
  const f32x4 zero = {0.f, 0.f, 0.f, 0.f};
#pragma unroll
  for (int i = 0; i < 4; ++i)
#pragma unroll
    for (int j = 0; j < 4; ++j) acc[i][j] = zero;

  auto STAGE = [&](int b, int t) {    // 6 gloads/thread per tile
    const int k0b = t * 128;
#pragma unroll
    for (int q = 0; q < 2; ++q)
      gload16(baseA[q] + k0b, &As[b * 16384 + (w * 2 + q) * 1024]);
#pragma unroll
    for (int q = 0; q < 4; ++q)
      gload16(baseB[q] + k0b, &Bs[b * 32768 + (w * 4 + q) * 1024]);
  };
  auto COMPUTE = [&](int b) {
    const char* Ab = &As[b * 16384];
    const char* Bb = &Bs[b * 32768];
    bf16x8 af[2][4], bfr[2][4];
#pragma unroll
    for (int ks = 0; ks < 2; ++ks) {
      const int colb = ks * 64 + ((l >> 4) << 4);
#pragma unroll
      for (int mi = 0; mi < 4; ++mi) {
        const int row = wm * 64 + mi * 16 + (l & 15);
        af[ks][mi] = *(const bf16x8*)&Ab[row * 128 + (colb ^ ((row & 7) << 4))];
      }
#pragma unroll
      for (int ni = 0; ni < 4; ++ni) {
        const int row = wn * 64 + ni * 16 + (l & 15);
        bfr[ks][ni] = *(const bf16x8*)&Bb[row * 128 + (colb ^ ((row & 7) << 4))];
      }
    }
    __builtin_amdgcn_s_setprio(1);
#pragma unroll
    for (int ks = 0; ks < 2; ++ks)
#pragma unroll
      for (int mi = 0; mi < 4; ++mi)
#pragma unroll
        for (int ni = 0; ni < 4; ++ni)
          acc[mi][ni] = mfma16(af[ks][mi], bfr[ks][ni], acc[mi][ni]);
    __builtin_amdgcn_s_setprio(0);
  };

  const int NT = HID / 64;            // 32
  STAGE(0, 0); STAGE(1, 1);
  WAITV(6); BAR();
  for (int t = 0; t < NT - 2; ++t) {
    STAGE((t + 2) % 3, t + 2);
    COMPUTE(t % 3);
    WAITV(6); BAR();
  }
  COMPUTE((NT - 2) % 3);
  WAITV(0); BAR();
  COMPUTE((NT - 1) % 3);

  const int cbase = n0 + wn * 32;
#pragma unroll
  for (int mi = 0; mi < 4; ++mi) {
    const int rb = wm * 64 + mi * 16 + ((l >> 4) << 2);
#pragma unroll
    for (int r = 0; r < 4; ++r) {
      const int row = m0 + rb + r;
      if (row < cnt) {
        const float wgt = rw[seg0 + row];
#pragma unroll
        for (int ni = 0; ni < 2; ++ni) {
          const float g = acc[mi][ni][r];
          const float u = acc[mi][ni + 2][r];
          const float s = g / (1.f + __expf(-g));
          ACT[(size_t)(seg0 + row) * IMED + cbase + ni * 16 + (l & 15)] = (__bf16)(s * u * wgt);
        }
      }
    }
  }
}

// ---------- GEMM2: BM=128 pairs x BN=256 H-cols, K=768, same pipeline, atomic scatter ----
__global__ __launch_bounds__(512, 2) void moe_gemm2(
    const __bf16* __restrict__ ACT, const __bf16* __restrict__ WdT,
    const int* __restrict__ rtok, const int* __restrict__ meta,
    float* __restrict__ out) {
  const int orig = blockIdx.x;        // 2048 WGs = 8 x 256
  const int wgid = (orig & 7) * 256 + (orig >> 3);
  const int e   = wgid >> 7;
  const int rem = wgid & 127;
  const int ny  = rem >> 4;
  const int mx  = rem & 15;

  const int seg0 = meta[16 + e];
  const int cnt  = meta[16 + e + 1] - seg0;
  const int m0 = mx * 128;
  if (m0 >= cnt) return;
  const int n0 = ny * 256;

  __shared__ __align__(16) char As[3 * 16384];
  __shared__ __align__(16) char Bs[3 * 32768];

  const int tid = threadIdx.x;
  const int l = tid & 63;
  const int w = tid >> 6;
  const int wm = w >> 2, wn = w & 3;
  const int swoff = 16 * ((l & 7) ^ (l >> 3));

  const char* baseA[2];
  const char* baseB[4];
#pragma unroll
  for (int q = 0; q < 2; ++q) {
    const int r = (w * 2 + q) * 8 + (l >> 3);
    int grow = m0 + r; if (grow >= cnt) grow = cnt - 1;
    baseA[q] = (const char*)(ACT + (size_t)(seg0 + grow) * IMED) + swoff;
  }
#pragma unroll
  for (int q = 0; q < 4; ++q) {
    const int r = (w * 4 + q) * 8 + (l >> 3);
    baseB[q] = (const char*)(WdT + ((size_t)e * HID + n0 + r) * IMED) + swoff;
  }

  f32x4 acc[4][4];
  const f32x4 zero = {0.f, 0.f, 0.f, 0.f};
#pragma unroll
  for (int i = 0; i < 4; ++i)
#pragma unroll
    for (int j = 0; j < 4; ++j) acc[i][j] = zero;

  auto STAGE = [&](int b, int t) {
    const int k0b = t * 128;
#pragma unroll
    for (int q = 0; q < 2; ++q)
      gload16(baseA[q] + k0b, &As[b * 16384 + (w * 2 + q) * 1024]);
#pragma unroll
    for (int q = 0; q < 4; ++q)
      gload16(baseB[q] + k0b, &Bs[b * 32768 + (w * 4 + q) * 1024]);
  };
  auto COMPUTE = [&](int b) {
    const char* Ab = &As[b * 16384];
    const char* Bb = &Bs[b * 32768];
    bf16x8 af[2][4], bfr[2][4];
#pragma unroll
    for (int ks = 0; ks < 2; ++ks) {
      const int colb = ks * 64 + ((l >> 4) << 4);
#pragma unroll
      for (int mi = 0; mi < 4; ++mi) {
        const int row = wm * 64 + mi * 16 + (l & 15);
        af[ks][mi] = *(const bf16x8*)&Ab[row * 128 + (colb ^ ((row & 7) << 4))];
      }
#pragma unroll
      for (int ni = 0; ni < 4; ++ni) {
        const int row = wn * 64 + ni * 16 + (l & 15);
        bfr[ks][ni] = *(const bf16x8*)&Bb[row * 128 + (colb ^ ((row & 7) << 4))];
      }
    }
    __builtin_amdgcn_s_setprio(1);
#pragma unroll
    for (int ks = 0; ks < 2; ++ks)
#pragma unroll
      for (int mi = 0; mi < 4; ++mi)
#pragma unroll
        for (int ni = 0; ni < 4; ++ni)
          acc[mi][ni] = mfma16(af[ks][mi], bfr[ks][ni], acc[mi][ni]);
    __builtin_amdgcn_s_setprio(0);
  };

  const int NT = IMED / 64;           // 12
  STAGE(0, 0); STAGE(1, 1);
  WAITV(6); BAR();
  for (int t = 0; t < NT - 2; ++t) {
    STAGE((t + 2) % 3, t + 2);
    COMPUTE(t % 3);
    WAITV(6); BAR();
  }
  COMPUTE((NT - 2) % 3);
  WAITV(0); BAR();
  COMPUTE((NT - 1) % 3);

#pragma unroll
  for (int mi = 0; mi < 4; ++mi) {
    const int rb = wm * 64 + mi * 16 + ((l >> 4) << 2);
#pragma unroll
    for (int r = 0; r < 4; ++r) {
      const int row = m0 + rb + r;
      if (row < cnt) {
        const int tok = rtok[seg0 + row];
#pragma unroll
        for (int ni = 0; ni < 4; ++ni)
          atomicAdd(&out[(size_t)tok * HID + n0 + wn * 64 + ni * 16 + (l & 15)],
                    acc[mi][ni][r]);
      }
    }
  }
}

extern "C" void kernel_launch(void* const* d_in, const int* in_sizes, int n_in,
                              void* d_out, int out_size, void* d_ws, size_t ws_size,
                              hipStream_t stream) {
  const float* X   = (const float*)d_in[0];
  const float* GUP = (const float*)d_in[1];
  const float* DP  = (const float*)d_in[2];
  const int*   IDX = (const int*)d_in[3];
  const float* W   = (const float*)d_in[4];
  float* out = (float*)d_out;

  size_t off = 0;
  auto alloc = [&](size_t bytes) -> void* {
    void* p = (char*)d_ws + off;
    off = (off + bytes + 255) & ~(size_t)255;
    return p;
  };
  __bf16* XB      = (__bf16*)alloc((size_t)T_TOK * HID * 2);
  __bf16* WguT    = (__bf16*)alloc((size_t)NEXP * 2 * IMED * HID * 2);
  __bf16* WdT     = (__bf16*)alloc((size_t)NEXP * HID * IMED * 2);
  __bf16* ACT     = (__bf16*)alloc((size_t)(MAXPAIR + 128) * IMED * 2);
  float*  combine = (float*)alloc((size_t)T_TOK * NEXP * 4);
  int*    meta    = (int*)alloc(64 * 4);
  int*    rtok    = (int*)alloc((size_t)MAXPAIR * 4);
  float*  rw      = (float*)alloc((size_t)MAXPAIR * 4);
  if (off > ws_size) return;

  hipMemsetAsync(meta, 0, 256, stream);
  moe_cvt_x<<<T_TOK * HID / (256 * 8), 256, 0, stream>>>(X, XB);
  moe_transpose<<<dim3((2 * IMED) / 64, HID / 64, NEXP), 256, 0, stream>>>(GUP, WguT, HID, 2 * IMED);
  moe_transpose<<<dim3(HID / 64, IMED / 64, NEXP), 256, 0, stream>>>(DP, WdT, IMED, HID);
  moe_route_build<<<T_TOK / 256, 256, 0, stream>>>(IDX, W, combine, meta);
  moe_scan<<<1, 64, 0, stream>>>(meta);
  moe_scatter<<<T_TOK / 256, 256, 0, stream>>>(combine, meta, rtok, rw);
  hipMemsetAsync(d_out, 0, (size_t)T_TOK * HID * 4, stream);
  moe_gemm1<<<1536, 512, 0, stream>>>(XB, WguT, rtok, rw, meta, ACT);
  moe_gemm2<<<2048, 512, 0, stream>>>(ACT, WdT, rtok, meta, out);
}